// Round 10
// baseline (41.894 us; speedup 1.0000x reference)
//
#include <hip/hip_runtime.h>
#include <hip/hip_fp16.h>

#define RS 7
#define SR 2
#define PD 10
#define CH (PD * RS * RS)   // 490
#define SCALE (1.0f / 16.0f)
#define HH 100
#define WW 100
#define NPLANE (HH * WW)    // 10000
#define NP4 (NPLANE / 4)    // 2500 uint4 slots per pair-plane
#define NB 4
#define MAXN 4096
#define TPB 1024
#define NBLK 256
#define NTILE (NB * CH / 2) // 980 pair-tiles

__device__ __forceinline__ unsigned pack_h2(float a, float b) {
    __half2 h = __floats2half2_rn(a, b);   // lo=A, hi=B
    return __builtin_bit_cast(unsigned, h);
}
__device__ __forceinline__ __half2 u2h2(unsigned u) {
    return __builtin_bit_cast(__half2, u);
}

__device__ __forceinline__ void psroi_sample2_h2(
    const unsigned* __restrict__ plane,
    float sw, float sh, float bw, float bh, int ph, int pw,
    float& outA, float& outB)
{
    float accA = 0.0f, accB = 0.0f;
    #pragma unroll
    for (int iy = 0; iy < SR; ++iy) {
        float y  = sh + ((float)ph + ((float)iy + 0.5f) * (1.0f / SR)) * bh;
        bool  vy = (y >= -1.0f) && (y <= (float)HH);
        float yy = fmaxf(y, 0.0f);
        int   y0 = min((int)floorf(yy), HH - 1);
        int   y1 = min(y0 + 1, HH - 1);
        float yc = (y0 >= HH - 1) ? (float)y0 : yy;
        float ly = yc - (float)y0;
        float hy = 1.0f - ly;
        #pragma unroll
        for (int ix = 0; ix < SR; ++ix) {
            float x  = sw + ((float)pw + ((float)ix + 0.5f) * (1.0f / SR)) * bw;
            bool  vx = (x >= -1.0f) && (x <= (float)WW);
            float xx = fmaxf(x, 0.0f);
            int   x0 = min((int)floorf(xx), WW - 1);
            int   x1 = min(x0 + 1, WW - 1);
            float xc = (x0 >= WW - 1) ? (float)x0 : xx;
            float lx = xc - (float)x0;
            float hx = 1.0f - lx;
            if (vy && vx) {
                __half2 v00 = u2h2(plane[y0 * WW + x0]);
                __half2 v01 = u2h2(plane[y0 * WW + x1]);
                __half2 v10 = u2h2(plane[y1 * WW + x0]);
                __half2 v11 = u2h2(plane[y1 * WW + x1]);
                __half2 s = __hmul2(__float2half2_rn(hy * hx), v00);
                s = __hfma2(__float2half2_rn(hy * lx), v01, s);
                s = __hfma2(__float2half2_rn(ly * hx), v10, s);
                s = __hfma2(__float2half2_rn(ly * lx), v11, s);
                accA += __low2float(s);
                accB += __high2float(s);
            }
        }
    }
    outA = accA * (1.0f / (SR * SR));
    outB = accB * (1.0f / (SR * SR));
}

// ---- persistent double-buffered kernel: 256 blocks x 1024 thr, ~4 tiles each ----
__global__ __launch_bounds__(TPB) void psroi_persist_kernel(
    const float* __restrict__ feat, const float* __restrict__ rois,
    float* __restrict__ out, int N)
{
    __shared__ __align__(16) unsigned buf0[NPLANE];   // 40 KB
    __shared__ __align__(16) unsigned buf1[NPLANE];   // 40 KB
    __shared__ unsigned short list[MAXN];             // 8 KB
    __shared__ int lcnt;

    int tid = threadIdx.x;
    int bid = blockIdx.x;

    // contiguous tile range for this block
    int base = NTILE / NBLK, rem = NTILE % NBLK;
    int t0 = bid * base + min(bid, rem);
    int t1 = t0 + base + (bid < rem ? 1 : 0);
    if (t0 >= t1) return;

    auto decode = [&](int T, int& b, int& cin1, int& cin2, int& ph, int& pw) {
        b = T / (CH / 2);
        int r = T - b * (CH / 2);
        int j = r / (RS * RS);
        int pp = r - j * (RS * RS);
        ph = pp / RS; pw = pp - ph * RS;
        cin1 = (2 * j) * (RS * RS) + pp;
        cin2 = cin1 + (RS * RS);
    };

    auto scan = [&](int bb) {   // callers handle surrounding barriers
        int lane = tid & 63;
        for (int k0 = 0; k0 < N; k0 += TPB) {
            int k = k0 + tid;
            bool m = (k < N) && ((int)rois[(size_t)k * 5] == bb);
            unsigned long long msk = __ballot(m);
            if (m) {
                int rank   = __popcll(msk & ((1ull << lane) - 1ull));
                int leader = __ffsll((long long)msk) - 1;
                int pos = 0;
                if (lane == leader) pos = atomicAdd(&lcnt, (int)__popcll(msk));
                pos = __shfl(pos, leader);
                list[pos + rank] = (unsigned short)k;
            }
        }
    };

    float4 rA0, rA1, rA2, rB0, rB1, rB2;
    int i2 = tid + 2 * TPB;                    // third slot (valid for tid<452)

    auto issue = [&](int b, int cin1, int cin2) {
        const float4* sA = (const float4*)(feat + (size_t)(b * CH + cin1) * NPLANE);
        const float4* sB = (const float4*)(feat + (size_t)(b * CH + cin2) * NPLANE);
        rA0 = sA[tid]; rA1 = sA[tid + TPB];
        rB0 = sB[tid]; rB1 = sB[tid + TPB];
        if (i2 < NP4) { rA2 = sA[i2]; rB2 = sB[i2]; }
    };

    auto commit = [&](unsigned* buf) {
        uint4* d = (uint4*)buf;
        uint4 u;
        u.x = pack_h2(rA0.x, rB0.x); u.y = pack_h2(rA0.y, rB0.y);
        u.z = pack_h2(rA0.z, rB0.z); u.w = pack_h2(rA0.w, rB0.w);
        d[tid] = u;
        u.x = pack_h2(rA1.x, rB1.x); u.y = pack_h2(rA1.y, rB1.y);
        u.z = pack_h2(rA1.z, rB1.z); u.w = pack_h2(rA1.w, rB1.w);
        d[tid + TPB] = u;
        if (i2 < NP4) {
            u.x = pack_h2(rA2.x, rB2.x); u.y = pack_h2(rA2.y, rB2.y);
            u.z = pack_h2(rA2.z, rB2.z); u.w = pack_h2(rA2.w, rB2.w);
            d[i2] = u;
        }
    };

    // ---- prologue: list + first tile staged ----
    int bC, cin1C, cin2C, phC, pwC;
    decode(t0, bC, cin1C, cin2C, phC, pwC);
    if (tid == 0) lcnt = 0;
    __syncthreads();
    scan(bC);
    issue(bC, cin1C, cin2C);
    commit(buf0);
    __syncthreads();
    int cur = 0;

    // ---- main pipelined loop ----
    for (int T = t0; T < t1; ++T) {
        bool has_next = (T + 1 < t1);
        int bN = bC, cin1N = 0, cin2N = 0, phN = 0, pwN = 0;
        if (has_next) {
            decode(T + 1, bN, cin1N, cin2N, phN, pwN);
            issue(bN, cin1N, cin2N);           // next tile's loads in flight
        }

        // compute current tile
        {
            const unsigned* buf = cur ? buf1 : buf0;
            int cnt = lcnt;
            for (int i = tid; i < cnt; i += TPB) {
                int n = list[i];
                const float* rp = rois + (size_t)n * 5;
                float sw = rp[1] * SCALE - 0.5f;
                float sh = rp[2] * SCALE - 0.5f;
                float bw = (rp[3] * SCALE - 0.5f - sw) * (1.0f / RS);
                float bh = (rp[4] * SCALE - 0.5f - sh) * (1.0f / RS);
                float vA, vB;
                psroi_sample2_h2(buf, sw, sh, bw, bh, phC, pwC, vA, vB);
                out[(size_t)n * CH + cin1C] = vA;
                out[(size_t)n * CH + cin2C] = vB;
            }
        }

        if (has_next) {
            if (bN != bC) {                     // batch boundary: rebuild list
                __syncthreads();                // everyone done reading old list
                if (tid == 0) lcnt = 0;
                __syncthreads();
                scan(bN);
            }
            commit(cur ? buf0 : buf1);          // loads arrived during compute
            __syncthreads();                    // buffer + list ready
            cur ^= 1;
            bC = bN; cin1C = cin1N; cin2C = cin2N; phC = phN; pwC = pwN;
        }
    }
}

// ---- fp32 direct-gather fallback for N > MAXN ----
__device__ __forceinline__ float psroi_sample_f32(const float* __restrict__ plane,
                                                  float sw, float sh, float bw, float bh,
                                                  int ph, int pw)
{
    float acc = 0.0f;
    #pragma unroll
    for (int iy = 0; iy < SR; ++iy) {
        float y  = sh + ((float)ph + ((float)iy + 0.5f) * (1.0f / SR)) * bh;
        bool  vy = (y >= -1.0f) && (y <= (float)HH);
        float yy = fmaxf(y, 0.0f);
        int   y0 = min((int)floorf(yy), HH - 1);
        int   y1 = min(y0 + 1, HH - 1);
        float yc = (y0 >= HH - 1) ? (float)y0 : yy;
        float ly = yc - (float)y0;
        float hy = 1.0f - ly;
        #pragma unroll
        for (int ix = 0; ix < SR; ++ix) {
            float x  = sw + ((float)pw + ((float)ix + 0.5f) * (1.0f / SR)) * bw;
            bool  vx = (x >= -1.0f) && (x <= (float)WW);
            float xx = fmaxf(x, 0.0f);
            int   x0 = min((int)floorf(xx), WW - 1);
            int   x1 = min(x0 + 1, WW - 1);
            float xc = (x0 >= WW - 1) ? (float)x0 : xx;
            float lx = xc - (float)x0;
            float hx = 1.0f - lx;
            float v00 = plane[y0 * WW + x0];
            float v01 = plane[y0 * WW + x1];
            float v10 = plane[y1 * WW + x0];
            float v11 = plane[y1 * WW + x1];
            float v = hy * (hx * v00 + lx * v01) + ly * (hx * v10 + lx * v11);
            if (vy && vx) acc += v;
        }
    }
    return acc * (1.0f / (SR * SR));
}

__global__ __launch_bounds__(256) void psroi_naive_kernel(
    const float* __restrict__ feat, const float* __restrict__ rois,
    float* __restrict__ out, int total)
{
    int o = blockIdx.x * blockDim.x + threadIdx.x;
    if (o >= total) return;
    int cin = o % CH;
    int n   = o / CH;
    int pw  = cin % RS;
    int ph  = (cin / RS) % RS;
    const float* r = rois + (size_t)n * 5;
    int bidx = (int)r[0];
    float sw = r[1] * SCALE - 0.5f;
    float sh = r[2] * SCALE - 0.5f;
    float bw = (r[3] * SCALE - 0.5f - sw) * (1.0f / RS);
    float bh = (r[4] * SCALE - 0.5f - sh) * (1.0f / RS);
    const float* base = feat + (size_t)(bidx * CH + cin) * NPLANE;
    out[o] = psroi_sample_f32(base, sw, sh, bw, bh, ph, pw);
}

extern "C" void kernel_launch(void* const* d_in, const int* in_sizes, int n_in,
                              void* d_out, int out_size, void* d_ws, size_t ws_size,
                              hipStream_t stream) {
    const float* feat = (const float*)d_in[0];
    const float* rois = (const float*)d_in[1];
    float* out = (float*)d_out;
    int N = in_sizes[1] / 5;

    if (N <= MAXN) {
        psroi_persist_kernel<<<NBLK, TPB, 0, stream>>>(feat, rois, out, N);
    } else {
        int total = N * CH;
        psroi_naive_kernel<<<(total + 255) / 256, 256, 0, stream>>>(feat, rois, out, total);
    }
}

// Round 11
// 31.012 us; speedup vs baseline: 1.3509x; 1.3509x over previous
//
#include <hip/hip_runtime.h>

#define RS 7
#define SR 2
#define PD 10
#define CH (PD * RS * RS)   // 490
#define SCALE (1.0f / 16.0f)
#define HH 100
#define WW 100
#define NPLANE (HH * WW)    // 10000
#define PADP 104            // pad floats (max index o+WW+1 = 10100)
#define BUFSZ (NPLANE + PADP)
#define MAXN 4096
#define TPB 1024
#define NBLK 256
#define SLICE 245           // tiles (cins) per XCD slice: 1960/8

// ---- async global->LDS, 16B per lane ----
__device__ __forceinline__ void gll16(const void* g, void* l) {
    __builtin_amdgcn_global_load_lds(
        (const __attribute__((address_space(1))) void*)g,
        (__attribute__((address_space(3))) void*)l, 16, 0, 0);
}

// ---- persistent streaming kernel: 256 blocks (1/CU), dbuf fp32 planes ----
__global__ __launch_bounds__(TPB) void psroi_stream_kernel(
    const float* __restrict__ feat, const float* __restrict__ rois,
    float* __restrict__ out, int N)
{
    __shared__ __align__(16) float buf0[BUFSZ];   // 40.4 KB
    __shared__ __align__(16) float buf1[BUFSZ];   // 40.4 KB
    __shared__ unsigned short list[MAXN];         // 8 KB
    __shared__ int lcnt;

    int tid = threadIdx.x;
    int bid = blockIdx.x;
    int xcd = bid & 7;          // heuristic XCD id (perf-only)
    int j   = bid >> 3;         // 0..31 within XCD
    int b   = xcd >> 1;         // one batch per slice: 1960 = 4b x 490, 490 = 2x245
    int cin0 = (xcd & 1) * SLICE + j;   // this block's k-th tile: cin0 + k*32
    int nt  = (SLICE - 1 - j) / 32 + 1; // 7 or 8 tiles

    // zero the pad rows of both buffers; init list count
    if (tid < PADP) { buf0[NPLANE + tid] = 0.0f; buf1[NPLANE + tid] = 0.0f; }
    if (tid == 0) lcnt = 0;
    __syncthreads();

    // stage first tile via DMA (issues immediately; latency hidden under scan)
    auto stage = [&](float* dst, int cin) {
        const char* gs = (const char*)(feat + (size_t)(b * CH + cin) * NPLANE);
        char* ls = (char*)dst;
        int wbase = tid & ~63;                       // wave-uniform LDS base
        #pragma unroll
        for (int c = 0; c < 3; ++c) {
            int slot = c * TPB + tid;
            if (slot < NPLANE / 4)                   // 2500 16B slots
                gll16(gs + (size_t)slot * 16, ls + (size_t)(c * TPB + wbase) * 16);
        }
    };
    stage(buf0, cin0);

    // build ROI list for this slice's batch (once per block), under DMA latency
    {
        int lane = tid & 63;
        for (int k0 = 0; k0 < N; k0 += TPB) {
            int k = k0 + tid;
            bool m = (k < N) && ((int)rois[(size_t)k * 5] == b);
            unsigned long long msk = __ballot(m);
            if (m) {
                int rank   = __popcll(msk & ((1ull << lane) - 1ull));
                int leader = __ffsll((long long)msk) - 1;
                int pos = 0;
                if (lane == leader) pos = atomicAdd(&lcnt, (int)__popcll(msk));
                pos = __shfl(pos, leader);
                list[pos + rank] = (unsigned short)k;
            }
        }
    }
    __syncthreads();   // drain DMA (vmcnt) + make list visible

    for (int k = 0; k < nt; ++k) {
        const float* __restrict__ bc = (k & 1) ? buf1 : buf0;
        float* bn = (k & 1) ? buf0 : buf1;
        int cin = cin0 + k * 32;
        if (k + 1 < nt) stage(bn, cin + 32);         // next tile's DMA in flight
        __builtin_amdgcn_sched_barrier(0);           // keep issue before compute

        int pw = cin % RS;
        int ph = (cin / RS) % RS;
        int cnt = lcnt;
        for (int i = tid; i < cnt; i += TPB) {
            int n = list[i];
            const float* rp = rois + (size_t)n * 5;
            float sw = rp[1] * SCALE - 0.5f;
            float sh = rp[2] * SCALE - 0.5f;
            float bw = (rp[3] * SCALE - 0.5f - sw) * (1.0f / RS);
            float bh = (rp[4] * SCALE - 0.5f - sh) * (1.0f / RS);
            float acc = 0.0f;
            #pragma unroll
            for (int iy = 0; iy < SR; ++iy) {
                float y  = sh + ((float)ph + ((float)iy + 0.5f) * (1.0f / SR)) * bh;
                bool  vy = (y >= -1.0f) && (y <= (float)HH);
                float yy = fmaxf(y, 0.0f);
                int   y0 = min((int)floorf(yy), HH - 1);
                float yc = (y0 >= HH - 1) ? (float)y0 : yy;
                float ly = yc - (float)y0;
                float hy = 1.0f - ly;
                #pragma unroll
                for (int ix = 0; ix < SR; ++ix) {
                    float x  = sw + ((float)pw + ((float)ix + 0.5f) * (1.0f / SR)) * bw;
                    bool  vx = (x >= -1.0f) && (x <= (float)WW);
                    float xx = fmaxf(x, 0.0f);
                    int   x0 = min((int)floorf(xx), WW - 1);
                    float xc = (x0 >= WW - 1) ? (float)x0 : xx;
                    float lx = xc - (float)x0;
                    float hx = 1.0f - lx;
                    // clamp-by-weight: out-of-plane taps land in zeroed pad or
                    // finite neighbor data with exactly-zero weight
                    int o = y0 * WW + x0;
                    float v00 = bc[o],      v01 = bc[o + 1];
                    float v10 = bc[o + WW], v11 = bc[o + WW + 1];
                    float v = hy * (hx * v00 + lx * v01) + ly * (hx * v10 + lx * v11);
                    if (vy && vx) acc += v;
                }
            }
            out[(size_t)n * CH + cin] = acc * (1.0f / (SR * SR));
        }
        __syncthreads();   // drains vmcnt (next tile committed) + all reads done
    }
}

// ---- general fallback (any B / N > MAXN): direct-gather per output ----
__global__ __launch_bounds__(256) void psroi_naive_kernel(
    const float* __restrict__ feat, const float* __restrict__ rois,
    float* __restrict__ out, int total)
{
    int o = blockIdx.x * blockDim.x + threadIdx.x;
    if (o >= total) return;
    int cin = o % CH;
    int n   = o / CH;
    int pw  = cin % RS;
    int ph  = (cin / RS) % RS;
    const float* r = rois + (size_t)n * 5;
    int bidx = (int)r[0];
    float sw = r[1] * SCALE - 0.5f;
    float sh = r[2] * SCALE - 0.5f;
    float bw = (r[3] * SCALE - 0.5f - sw) * (1.0f / RS);
    float bh = (r[4] * SCALE - 0.5f - sh) * (1.0f / RS);
    const float* base = feat + (size_t)(bidx * CH + cin) * NPLANE;
    float acc = 0.0f;
    #pragma unroll
    for (int iy = 0; iy < SR; ++iy) {
        float y  = sh + ((float)ph + ((float)iy + 0.5f) * (1.0f / SR)) * bh;
        bool  vy = (y >= -1.0f) && (y <= (float)HH);
        float yy = fmaxf(y, 0.0f);
        int   y0 = min((int)floorf(yy), HH - 1);
        int   y1 = min(y0 + 1, HH - 1);
        float yc = (y0 >= HH - 1) ? (float)y0 : yy;
        float ly = yc - (float)y0;
        float hy = 1.0f - ly;
        #pragma unroll
        for (int ix = 0; ix < SR; ++ix) {
            float x  = sw + ((float)pw + ((float)ix + 0.5f) * (1.0f / SR)) * bw;
            bool  vx = (x >= -1.0f) && (x <= (float)WW);
            float xx = fmaxf(x, 0.0f);
            int   x0 = min((int)floorf(xx), WW - 1);
            int   x1 = min(x0 + 1, WW - 1);
            float xc = (x0 >= WW - 1) ? (float)x0 : xx;
            float lx = xc - (float)x0;
            float hx = 1.0f - lx;
            float v00 = base[y0 * WW + x0];
            float v01 = base[y0 * WW + x1];
            float v10 = base[y1 * WW + x0];
            float v11 = base[y1 * WW + x1];
            float v = hy * (hx * v00 + lx * v01) + ly * (hx * v10 + lx * v11);
            if (vy && vx) acc += v;
        }
    }
    out[o] = acc * (1.0f / (SR * SR));
}

extern "C" void kernel_launch(void* const* d_in, const int* in_sizes, int n_in,
                              void* d_out, int out_size, void* d_ws, size_t ws_size,
                              hipStream_t stream) {
    const float* feat = (const float*)d_in[0];
    const float* rois = (const float*)d_in[1];
    float* out = (float*)d_out;
    int N = in_sizes[1] / 5;
    int B = in_sizes[0] / (CH * NPLANE);

    if (N <= MAXN && B == 4) {
        psroi_stream_kernel<<<NBLK, TPB, 0, stream>>>(feat, rois, out, N);
    } else {
        int total = N * CH;
        psroi_naive_kernel<<<(total + 255) / 256, 256, 0, stream>>>(feat, rois, out, total);
    }
}